// Round 1
// baseline (480.801 us; speedup 1.0000x reference)
//
#include <hip/hip_runtime.h>

typedef __attribute__((ext_vector_type(8))) short short8;
typedef __attribute__((ext_vector_type(4))) float f32x4;
typedef __attribute__((ext_vector_type(4))) unsigned short us4;

#define NTOK 343
#define BMP 344      // bias/mask padded row pitch (elements)
#define VTP 352      // v_t padded row pitch (elements)
#define NT 22        // 22 tiles of 16 cover 352 >= 343

// ---- workspace layout (bytes) ----
#define OFF_QG   0u
#define OFF_KG   33718272u     // 256*6*343*32*2
#define OFF_VT   67436544u
#define OFF_AO   102039552u    // + 1536*32*352*2
#define OFF_BIAS 135757824u    // + 87808*192*2
#define OFF_MASK 137174016u    // bias: 6*343*344*2 = 1416144, padded
// mask end: 137174016 + 64*343*344*2 = 152276992 (+64 slack)

__device__ __forceinline__ unsigned short f2bf(float f) {
  union { float f; unsigned u; } v; v.f = f;
  unsigned r = v.u + 0x7FFFu + ((v.u >> 16) & 1u);
  return (unsigned short)(r >> 16);
}

__device__ __forceinline__ float bf2f(unsigned short b) {
  union { unsigned u; float f; } v; v.u = ((unsigned)b) << 16;
  return v.f;
}

__device__ __forceinline__ short8 ld8(const unsigned short* p) {
  return *reinterpret_cast<const short8*>(p);
}

__device__ __forceinline__ short8 cvt8(const float* p) {
  f32x4 a = *reinterpret_cast<const f32x4*>(p);
  f32x4 b = *reinterpret_cast<const f32x4*>(p + 4);
  short8 f;
  f[0] = (short)f2bf(a[0]); f[1] = (short)f2bf(a[1]);
  f[2] = (short)f2bf(a[2]); f[3] = (short)f2bf(a[3]);
  f[4] = (short)f2bf(b[0]); f[5] = (short)f2bf(b[1]);
  f[6] = (short)f2bf(b[2]); f[7] = (short)f2bf(b[3]);
  return f;
}

// ---------------- kernel B: precompute bias/mask bf16 + v_t pad zero ----------------
__global__ __launch_bounds__(256) void precompute(
    const float* __restrict__ mask, const float* __restrict__ table,
    const int* __restrict__ rel_idx,
    unsigned short* __restrict__ bias_bf, unsigned short* __restrict__ mask_bf,
    unsigned short* __restrict__ v_t)
{
  const int idx = blockIdx.x * 256 + threadIdx.x;
  const int NN = NTOK * NTOK;            // 117649
  if (idx < 64 * NN) {
    const int w = idx / NN, rem = idx - w * NN;
    const int i = rem / NTOK, j = rem - i * NTOK;
    mask_bf[(w * NTOK + i) * BMP + j] = f2bf(mask[idx]);
  }
  if (idx < 6 * NN) {
    const int h = idx / NN, rem = idx - h * NN;
    bias_bf[h * (NTOK * BMP) + (rem / NTOK) * BMP + (rem % NTOK)] =
        f2bf(table[rel_idx[rem] * 6 + h]);
  }
  if (idx < 1536 * 32 * 9) {
    const int row = idx / 9, cc = idx - row * 9;
    v_t[row * VTP + NTOK + cc] = 0;
  }
}

// ---------------- kernel A: fused Q/K/V projection ----------------
__global__ __launch_bounds__(256, 2) void proj_qkv(
    const float* __restrict__ x1, const float* __restrict__ x2,
    const float* __restrict__ qw, const float* __restrict__ qb,
    const float* __restrict__ kvw, const float* __restrict__ kvb,
    unsigned short* __restrict__ q_g, unsigned short* __restrict__ k_g,
    unsigned short* __restrict__ v_t)
{
  const int tid = threadIdx.x;
  const int wv = tid >> 6, lane = tid & 63, lg = lane >> 4, lr = lane & 15;
  const int twave = blockIdx.x * 128 + wv * 32;
  const int cblk = blockIdx.y;

  const float* X; const float* W; const float* Bv; int cbase; int path;
  if (cblk < 3)      { X = x1; W = qw;  Bv = qb;  cbase = cblk * 64;             path = 0; }
  else if (cblk < 6) { X = x2; W = kvw; Bv = kvb; cbase = (cblk - 3) * 64;       path = 1; }
  else               { X = x2; W = kvw; Bv = kvb; cbase = (cblk - 6) * 64 + 192; path = 2; }

  f32x4 acc[2][4];
  #pragma unroll
  for (int i = 0; i < 2; ++i)
    #pragma unroll
    for (int j = 0; j < 4; ++j) acc[i][j] = (f32x4){0.f, 0.f, 0.f, 0.f};

  #pragma unroll
  for (int kk = 0; kk < 6; ++kk) {
    const int k0 = kk * 32 + lg * 8;
    short8 afr[2];
    #pragma unroll
    for (int rs = 0; rs < 2; ++rs)
      afr[rs] = cvt8(X + (twave + rs * 16 + lr) * 192 + k0);
    short8 bfr[4];
    #pragma unroll
    for (int ct = 0; ct < 4; ++ct)
      bfr[ct] = cvt8(W + (cbase + ct * 16 + lr) * 192 + k0);
    #pragma unroll
    for (int rs = 0; rs < 2; ++rs)
      #pragma unroll
      for (int ct = 0; ct < 4; ++ct)
        acc[rs][ct] = __builtin_amdgcn_mfma_f32_16x16x32_bf16(afr[rs], bfr[ct], acc[rs][ct], 0, 0, 0);
  }

  const float scale = (path == 0) ? 0.17677669529663687f : 1.0f;
  #pragma unroll
  for (int ct = 0; ct < 4; ++ct) {
    const int c = cbase + ct * 16 + lr;
    const float bias = Bv[c];
    #pragma unroll
    for (int rs = 0; rs < 2; ++rs) {
      #pragma unroll
      for (int r = 0; r < 4; ++r) {
        const int t = twave + rs * 16 + lg * 4 + r;
        const int b = t / NTOK, n = t - b * NTOK;
        const unsigned short bv = f2bf((acc[rs][ct][r] + bias) * scale);
        if (path == 0) {
          const int h = c >> 5, d = c & 31;
          q_g[((b * 6 + h) * NTOK + n) * 32 + d] = bv;
        } else if (path == 1) {
          const int h = c >> 5, d = c & 31;
          k_g[((b * 6 + h) * NTOK + n) * 32 + d] = bv;
        } else {
          const int c2 = c - 192, h = c2 >> 5, d = c2 & 31;
          v_t[((b * 6 + h) * 32 + d) * VTP + n] = bv;
        }
      }
    }
  }
}

// ---------------- kernel C: attention (swapped-QK, per-wave independent) ----------------
__global__ __launch_bounds__(256, 2) void attn(
    const unsigned short* __restrict__ q_g, const unsigned short* __restrict__ k_g,
    const unsigned short* __restrict__ v_t, const unsigned short* __restrict__ bias_bf,
    const unsigned short* __restrict__ mask_bf, unsigned short* __restrict__ attn_out)
{
  __shared__ __align__(16) unsigned short p_lds[4][16][360];
  const int tid = threadIdx.x;
  const int wv = tid >> 6, lane = tid & 63, lg = lane >> 4, lr = lane & 15;
  const int bid = blockIdx.x;
  const int w = bid & 63, hh = bid >> 6, h = hh % 6, hf = hh / 6;

  const unsigned short* bias_h = bias_bf + h * (NTOK * BMP);
  const unsigned short* mask_w = mask_bf + w * (NTOK * BMP);

  for (int rt = 0; rt < 3; ++rt) {
    const int row0 = (hf * 3 + rt) * 64 + wv * 16;   // this wave's q-row base
    if (row0 >= NTOK) continue;                      // fully-invalid wave tile
    const int qrow = row0 + lr;
    const int qrc = qrow < NTOK ? qrow : NTOK - 1;
    const unsigned short* bmb = bias_h + qrc * BMP;
    const unsigned short* bmm = mask_w + qrc * BMP;

    for (int bo = 0; bo < 4; ++bo) {
      const int b = bo * 64 + w;
      const int bh = b * 6 + h;
      const unsigned short* qp = q_g + bh * (NTOK * 32);
      const unsigned short* kp = k_g + bh * (NTOK * 32);
      const unsigned short* vp = v_t + bh * (32 * VTP);

      // Q B-fragment: lane holds q[qrow=lr+row0][d = 8*lg .. +7]
      const short8 qf = ld8(qp + qrc * 32 + lg * 8);

      // S^T tiles: rows = k-tokens, cols = q-rows
      f32x4 s[NT];
      #pragma unroll
      for (int j = 0; j < NT; ++j) {
        const int kt = j * 16 + lr;
        const int ktc = kt < NTOK ? kt : NTOK - 1;
        const short8 kf = ld8(kp + ktc * 32 + lg * 8);
        const f32x4 z = {0.f, 0.f, 0.f, 0.f};
        s[j] = __builtin_amdgcn_mfma_f32_16x16x32_bf16(kf, qf, z, 0, 0, 0);
      }

      // bias + mask add, tail masking, per-q-row max (q-row == lane's col == lr)
      float mx = -1e30f;
      #pragma unroll
      for (int j = 0; j < NT; ++j) {
        const int kb = j * 16 + lg * 4;
        const us4 b4 = *reinterpret_cast<const us4*>(bmb + kb);
        const us4 m4 = *reinterpret_cast<const us4*>(bmm + kb);
        #pragma unroll
        for (int r = 0; r < 4; ++r) {
          const float bm = bf2f(b4[r]) + bf2f(m4[r]);
          const float v = (kb + r < NTOK) ? (s[j][r] + bm) : -1e30f;
          s[j][r] = v;
          mx = fmaxf(mx, v);
        }
      }
      mx = fmaxf(mx, __shfl_xor(mx, 16));
      mx = fmaxf(mx, __shfl_xor(mx, 32));

      float sum = 0.f;
      #pragma unroll
      for (int j = 0; j < NT; ++j) {
        us4 pk;
        #pragma unroll
        for (int r = 0; r < 4; ++r) {
          const float p = __expf(s[j][r] - mx);
          sum += p;
          pk[r] = f2bf(p);
        }
        *reinterpret_cast<us4*>(&p_lds[wv][lr][j * 16 + lg * 4]) = pk;
      }
      sum += __shfl_xor(sum, 16);
      sum += __shfl_xor(sum, 32);
      const float inv = 1.0f / sum;

      // PV: O[q,d] = sum_k P[q,k] V[k,d]
      f32x4 o0 = {0.f, 0.f, 0.f, 0.f}, o1 = {0.f, 0.f, 0.f, 0.f};
      #pragma unroll
      for (int kk = 0; kk < 11; ++kk) {
        const short8 pf = ld8(&p_lds[wv][lr][kk * 32 + lg * 8]);
        const short8 v0 = ld8(vp + lr * VTP + kk * 32 + lg * 8);
        const short8 v1 = ld8(vp + (16 + lr) * VTP + kk * 32 + lg * 8);
        o0 = __builtin_amdgcn_mfma_f32_16x16x32_bf16(pf, v0, o0, 0, 0, 0);
        o1 = __builtin_amdgcn_mfma_f32_16x16x32_bf16(pf, v1, o1, 0, 0, 0);
      }

      // redistribute 1/sum to O's row mapping, store
      float invr[4];
      #pragma unroll
      for (int r = 0; r < 4; ++r)
        invr[r] = __shfl(inv, (lane & 48) | (lg * 4 + r));
      #pragma unroll
      for (int r = 0; r < 4; ++r) {
        const int n = row0 + lg * 4 + r;
        if (n < NTOK) {
          unsigned short* op = attn_out + (b * NTOK + n) * 192 + h * 32;
          op[lr]      = f2bf(o0[r] * invr[r]);
          op[16 + lr] = f2bf(o1[r] * invr[r]);
        }
      }
    }
  }
}

// ---------------- kernel D: output projection ----------------
__global__ __launch_bounds__(256, 2) void proj_out(
    const unsigned short* __restrict__ a_in, const float* __restrict__ pw,
    const float* __restrict__ pb, float* __restrict__ out)
{
  const int tid = threadIdx.x;
  const int wv = tid >> 6, lane = tid & 63, lg = lane >> 4, lr = lane & 15;
  const int twave = blockIdx.x * 128 + wv * 32;
  const int cbase = blockIdx.y * 64;

  f32x4 acc[2][4];
  #pragma unroll
  for (int i = 0; i < 2; ++i)
    #pragma unroll
    for (int j = 0; j < 4; ++j) acc[i][j] = (f32x4){0.f, 0.f, 0.f, 0.f};

  #pragma unroll
  for (int kk = 0; kk < 6; ++kk) {
    const int k0 = kk * 32 + lg * 8;
    short8 afr[2];
    #pragma unroll
    for (int rs = 0; rs < 2; ++rs)
      afr[rs] = ld8(a_in + (twave + rs * 16 + lr) * 192 + k0);
    short8 bfr[4];
    #pragma unroll
    for (int ct = 0; ct < 4; ++ct)
      bfr[ct] = cvt8(pw + (cbase + ct * 16 + lr) * 192 + k0);
    #pragma unroll
    for (int rs = 0; rs < 2; ++rs)
      #pragma unroll
      for (int ct = 0; ct < 4; ++ct)
        acc[rs][ct] = __builtin_amdgcn_mfma_f32_16x16x32_bf16(afr[rs], bfr[ct], acc[rs][ct], 0, 0, 0);
  }

  #pragma unroll
  for (int ct = 0; ct < 4; ++ct) {
    const int c = cbase + ct * 16 + lr;
    const float bias = pb[c];
    #pragma unroll
    for (int rs = 0; rs < 2; ++rs) {
      #pragma unroll
      for (int r = 0; r < 4; ++r) {
        const int t = twave + rs * 16 + lg * 4 + r;
        out[t * 192 + c] = acc[rs][ct][r] + bias;
      }
    }
  }
}

extern "C" void kernel_launch(void* const* d_in, const int* in_sizes, int n_in,
                              void* d_out, int out_size, void* d_ws, size_t ws_size,
                              hipStream_t stream) {
  const float* x1    = (const float*)d_in[0];
  const float* x2    = (const float*)d_in[1];
  const float* mask  = (const float*)d_in[2];
  const float* table = (const float*)d_in[3];
  const float* qw    = (const float*)d_in[4];
  const float* qb    = (const float*)d_in[5];
  const float* kvw   = (const float*)d_in[6];
  const float* kvb   = (const float*)d_in[7];
  const float* pw    = (const float*)d_in[8];
  const float* pb    = (const float*)d_in[9];
  const int* rel_idx = (const int*)d_in[10];

  char* ws = (char*)d_ws;
  unsigned short* q_g     = (unsigned short*)(ws + OFF_QG);
  unsigned short* k_g     = (unsigned short*)(ws + OFF_KG);
  unsigned short* v_t     = (unsigned short*)(ws + OFF_VT);
  unsigned short* a_o     = (unsigned short*)(ws + OFF_AO);
  unsigned short* bias_bf = (unsigned short*)(ws + OFF_BIAS);
  unsigned short* mask_bf = (unsigned short*)(ws + OFF_MASK);

  hipLaunchKernelGGL(precompute, dim3(29413), dim3(256), 0, stream,
                     mask, table, rel_idx, bias_bf, mask_bf, v_t);
  hipLaunchKernelGGL(proj_qkv, dim3(686, 9), dim3(256), 0, stream,
                     x1, x2, qw, qb, kvw, kvb, q_g, k_g, v_t);
  hipLaunchKernelGGL(attn, dim3(768), dim3(256), 0, stream,
                     q_g, k_g, v_t, bias_bf, mask_bf, a_o);
  hipLaunchKernelGGL(proj_out, dim3(686, 3), dim3(256), 0, stream,
                     a_o, pw, pb, (float*)d_out);
}

// Round 2
// 382.677 us; speedup vs baseline: 1.2564x; 1.2564x over previous
//
#include <hip/hip_runtime.h>

typedef __attribute__((ext_vector_type(8))) short short8;
typedef __attribute__((ext_vector_type(4))) float f32x4;
typedef __attribute__((ext_vector_type(4))) unsigned short us4;

#define NTOK 343
#define BMP 344      // bias/mask padded row pitch (elements)
#define VTP 352      // v_t padded row pitch (elements)
#define NT 22        // 22 tiles of 16 cover 352 >= 343

// ---- workspace layout (bytes) ----
#define OFF_QG   0u
#define OFF_KG   33718272u     // 256*6*343*32*2
#define OFF_VT   67436544u
#define OFF_AO   102039552u    // x1b during precompute/proj; a_o afterwards
#define OFF_BIAS 135757824u
#define OFF_MASK 137174016u
#define OFF_WB   152276992u    // bf16 weights: wq(73728) | wkv(147456) | wp(73728)

__device__ __forceinline__ unsigned short f2bf(float f) {
  union { float f; unsigned u; } v; v.f = f;
  unsigned r = v.u + 0x7FFFu + ((v.u >> 16) & 1u);
  return (unsigned short)(r >> 16);
}

__device__ __forceinline__ float bf2f(unsigned short b) {
  union { unsigned u; float f; } v; v.u = ((unsigned)b) << 16;
  return v.f;
}

__device__ __forceinline__ short8 ld8(const unsigned short* p) {
  return *reinterpret_cast<const short8*>(p);
}

// ---------------- kernel B: precompute (bf16 conversions + bias gather + pads) ----------------
// ranges (256-thread granularity):
//  [0, 4214784)          x1 -> x1b (vec4)
//  [4214784, 8429568)    x2 -> x2b (vec4)
//  [8429568, 8466432)    weights -> bf16 (vec4)
//  [8466432, 10354304)   mask -> mask_bf (rows x 86 quads)
//  [10354304, 10471953)  bias gather (117649, x6 heads)
//  [10471953, 10521105)  v_t pad zero (49152 rows x 9)
__global__ __launch_bounds__(256) void precompute(
    const float* __restrict__ x1, const float* __restrict__ x2,
    const float* __restrict__ mask, const float* __restrict__ table,
    const int* __restrict__ rel_idx,
    const float* __restrict__ qw, const float* __restrict__ kvw, const float* __restrict__ pw,
    unsigned short* __restrict__ x1b, unsigned short* __restrict__ x2b,
    unsigned short* __restrict__ wq_bf, unsigned short* __restrict__ wkv_bf,
    unsigned short* __restrict__ wp_bf,
    unsigned short* __restrict__ bias_bf, unsigned short* __restrict__ mask_bf,
    unsigned short* __restrict__ v_t)
{
  const int idx = blockIdx.x * 256 + threadIdx.x;
  if (idx < 8429568) {
    const float* src; unsigned short* dst; int i;
    if (idx < 4214784) { src = x1; dst = x1b; i = idx; }
    else               { src = x2; dst = x2b; i = idx - 4214784; }
    f32x4 v = *reinterpret_cast<const f32x4*>(src + i * 4);
    us4 o; o[0] = f2bf(v[0]); o[1] = f2bf(v[1]); o[2] = f2bf(v[2]); o[3] = f2bf(v[3]);
    *reinterpret_cast<us4*>(dst + i * 4) = o;
  } else if (idx < 8466432) {
    const int wi = idx - 8429568;
    const float* src; unsigned short* dst; int i;
    if (wi < 9216)       { src = qw;  dst = wq_bf;  i = wi; }
    else if (wi < 27648) { src = kvw; dst = wkv_bf; i = wi - 9216; }
    else                 { src = pw;  dst = wp_bf;  i = wi - 27648; }
    f32x4 v = *reinterpret_cast<const f32x4*>(src + i * 4);
    us4 o; o[0] = f2bf(v[0]); o[1] = f2bf(v[1]); o[2] = f2bf(v[2]); o[3] = f2bf(v[3]);
    *reinterpret_cast<us4*>(dst + i * 4) = o;
  } else if (idx < 10354304) {
    const int mi = idx - 8466432;
    const int row = mi / 86, q = mi - row * 86;
    const int j0 = q * 4;
    const float* src = mask + row * NTOK + j0;
    unsigned short* dst = mask_bf + row * BMP + j0;
    if (q < 85) {
      us4 o; o[0] = f2bf(src[0]); o[1] = f2bf(src[1]); o[2] = f2bf(src[2]); o[3] = f2bf(src[3]);
      *reinterpret_cast<us4*>(dst) = o;
    } else {
      dst[0] = f2bf(src[0]); dst[1] = f2bf(src[1]); dst[2] = f2bf(src[2]);
    }
  } else if (idx < 10471953) {
    const int i = idx - 10354304;
    const int ri = rel_idx[i] * 6;
    const int rrow = i / NTOK, j = i - rrow * NTOK;
    unsigned short* dst = bias_bf + rrow * BMP + j;
    #pragma unroll
    for (int h = 0; h < 6; ++h) dst[h * (NTOK * BMP)] = f2bf(table[ri + h]);
  } else if (idx < 10521105) {
    const int row = idx - 10471953;
    unsigned short* dst = v_t + row * VTP + NTOK;
    #pragma unroll
    for (int c = 0; c < 9; ++c) dst[c] = 0;
  }
}

// ---------------- kernel A: fused Q/K/V projection (bf16 GEMM, 128x192 tile/block) ----------------
__global__ __launch_bounds__(256) void proj(
    const unsigned short* __restrict__ x1b, const unsigned short* __restrict__ x2b,
    const unsigned short* __restrict__ wq_bf, const unsigned short* __restrict__ wkv_bf,
    const float* __restrict__ qb, const float* __restrict__ kvb,
    unsigned short* __restrict__ q_g, unsigned short* __restrict__ k_g,
    unsigned short* __restrict__ v_t)
{
  const int tid = threadIdx.x;
  const int wv = tid >> 6, lane = tid & 63, lg = lane >> 4, lr = lane & 15;
  const int path = blockIdx.y;
  const int row0 = blockIdx.x * 128 + wv * 32;

  const unsigned short* X = (path == 0) ? x1b : x2b;
  const unsigned short* W = (path == 0) ? wq_bf : (path == 1 ? wkv_bf : wkv_bf + 36864);
  const float* Bv = (path == 0) ? qb : (path == 1 ? kvb : kvb + 192);

  f32x4 acc[2][12];
  #pragma unroll
  for (int i = 0; i < 2; ++i)
    #pragma unroll
    for (int j = 0; j < 12; ++j) acc[i][j] = (f32x4){0.f, 0.f, 0.f, 0.f};

  const unsigned short* xr0 = X + (row0 + lr) * 192;
  const unsigned short* xr1 = xr0 + 16 * 192;
  const unsigned short* wr  = W + lr * 192;

  if (path < 2) {
    #pragma unroll
    for (int kk = 0; kk < 6; ++kk) {
      const int k0 = kk * 32 + lg * 8;
      const short8 a0 = ld8(xr0 + k0);
      const short8 a1 = ld8(xr1 + k0);
      #pragma unroll
      for (int ct = 0; ct < 12; ++ct) {
        const short8 wf = ld8(wr + ct * 3072 + k0);
        acc[0][ct] = __builtin_amdgcn_mfma_f32_16x16x32_bf16(a0, wf, acc[0][ct], 0, 0, 0);
        acc[1][ct] = __builtin_amdgcn_mfma_f32_16x16x32_bf16(a1, wf, acc[1][ct], 0, 0, 0);
      }
    }
    // ---- epilogue Q/K: out[(b,h,n,d)] with C rows = tokens, cols = c ----
    unsigned short* out = (path == 0) ? q_g : k_g;
    const float scale = (path == 0) ? 0.17677669529663687f : 1.0f;
    float bs[12];
    #pragma unroll
    for (int ct = 0; ct < 12; ++ct) bs[ct] = Bv[ct * 16 + lr];
    #pragma unroll
    for (int rs = 0; rs < 2; ++rs) {
      const int t0 = row0 + rs * 16 + lg * 4;
      const int b0 = t0 / NTOK;
      const int n0 = t0 - b0 * NTOK;
      #pragma unroll
      for (int r = 0; r < 4; ++r) {
        int b = b0, n = n0 + r;
        if (n >= NTOK) { b++; n -= NTOK; }
        unsigned short* ob = out + (b * 6 * NTOK + n) * 32 + lr;
        #pragma unroll
        for (int ct = 0; ct < 12; ++ct) {
          const int h = ct >> 1, dhi = (ct & 1) * 16;
          ob[h * (NTOK * 32) + dhi] = f2bf((acc[rs][ct][r] + bs[ct]) * scale);
        }
      }
    }
  } else {
    #pragma unroll
    for (int kk = 0; kk < 6; ++kk) {
      const int k0 = kk * 32 + lg * 8;
      const short8 a0 = ld8(xr0 + k0);
      const short8 a1 = ld8(xr1 + k0);
      #pragma unroll
      for (int ct = 0; ct < 12; ++ct) {
        const short8 wf = ld8(wr + ct * 3072 + k0);
        acc[0][ct] = __builtin_amdgcn_mfma_f32_16x16x32_bf16(wf, a0, acc[0][ct], 0, 0, 0);
        acc[1][ct] = __builtin_amdgcn_mfma_f32_16x16x32_bf16(wf, a1, acc[1][ct], 0, 0, 0);
      }
    }
    // ---- epilogue V: C rows = c (output col), cols = tokens; v_t layout [bh][d][n] ----
    f32x4 bv[12];
    #pragma unroll
    for (int ct = 0; ct < 12; ++ct)
      bv[ct] = *reinterpret_cast<const f32x4*>(Bv + ct * 16 + lg * 4);
    #pragma unroll
    for (int tt = 0; tt < 2; ++tt) {
      const int t = row0 + tt * 16 + lr;
      const int b = t / NTOK;
      const int n = t - b * NTOK;
      unsigned short* vb = v_t + b * (6 * 32 * VTP) + n;
      #pragma unroll
      for (int ct = 0; ct < 12; ++ct) {
        unsigned short* vc = vb + (ct * 16 + lg * 4) * VTP;
        #pragma unroll
        for (int r = 0; r < 4; ++r) {
          vc[r * VTP] = f2bf(acc[tt][ct][r] + bv[ct][r]);
        }
      }
    }
  }
}

// ---------------- kernel C: attention (swapped-QK, per-wave independent) ----------------
__global__ __launch_bounds__(256, 2) void attn(
    const unsigned short* __restrict__ q_g, const unsigned short* __restrict__ k_g,
    const unsigned short* __restrict__ v_t, const unsigned short* __restrict__ bias_bf,
    const unsigned short* __restrict__ mask_bf, unsigned short* __restrict__ attn_out)
{
  __shared__ __align__(16) unsigned short p_lds[4][16][360];
  const int tid = threadIdx.x;
  const int wv = tid >> 6, lane = tid & 63, lg = lane >> 4, lr = lane & 15;
  const int bid = blockIdx.x;
  const int w = bid & 63, hh = bid >> 6, h = hh % 6, hf = hh / 6;

  const unsigned short* bias_h = bias_bf + h * (NTOK * BMP);
  const unsigned short* mask_w = mask_bf + w * (NTOK * BMP);

  for (int rt = 0; rt < 3; ++rt) {
    const int row0 = (hf * 3 + rt) * 64 + wv * 16;   // this wave's q-row base
    if (row0 >= NTOK) continue;                      // fully-invalid wave tile
    const int qrow = row0 + lr;
    const int qrc = qrow < NTOK ? qrow : NTOK - 1;
    const unsigned short* bmb = bias_h + qrc * BMP;
    const unsigned short* bmm = mask_w + qrc * BMP;

    for (int bo = 0; bo < 4; ++bo) {
      const int b = bo * 64 + w;
      const int bh = b * 6 + h;
      const unsigned short* qp = q_g + bh * (NTOK * 32);
      const unsigned short* kp = k_g + bh * (NTOK * 32);
      const unsigned short* vp = v_t + bh * (32 * VTP);

      // Q B-fragment: lane holds q[qrow=lr+row0][d = 8*lg .. +7]
      const short8 qf = ld8(qp + qrc * 32 + lg * 8);

      // S^T tiles: rows = k-tokens, cols = q-rows
      f32x4 s[NT];
      #pragma unroll
      for (int j = 0; j < NT; ++j) {
        const int kt = j * 16 + lr;
        const int ktc = kt < NTOK ? kt : NTOK - 1;
        const short8 kf = ld8(kp + ktc * 32 + lg * 8);
        const f32x4 z = {0.f, 0.f, 0.f, 0.f};
        s[j] = __builtin_amdgcn_mfma_f32_16x16x32_bf16(kf, qf, z, 0, 0, 0);
      }

      // bias + mask add, tail masking, per-q-row max (q-row == lane's col == lr)
      float mx = -1e30f;
      #pragma unroll
      for (int j = 0; j < NT; ++j) {
        const int kb = j * 16 + lg * 4;
        const us4 b4 = *reinterpret_cast<const us4*>(bmb + kb);
        const us4 m4 = *reinterpret_cast<const us4*>(bmm + kb);
        #pragma unroll
        for (int r = 0; r < 4; ++r) {
          const float bm = bf2f(b4[r]) + bf2f(m4[r]);
          const float v = (kb + r < NTOK) ? (s[j][r] + bm) : -1e30f;
          s[j][r] = v;
          mx = fmaxf(mx, v);
        }
      }
      mx = fmaxf(mx, __shfl_xor(mx, 16));
      mx = fmaxf(mx, __shfl_xor(mx, 32));

      float sum = 0.f;
      #pragma unroll
      for (int j = 0; j < NT; ++j) {
        us4 pk;
        #pragma unroll
        for (int r = 0; r < 4; ++r) {
          const float p = __expf(s[j][r] - mx);
          sum += p;
          pk[r] = f2bf(p);
        }
        *reinterpret_cast<us4*>(&p_lds[wv][lr][j * 16 + lg * 4]) = pk;
      }
      sum += __shfl_xor(sum, 16);
      sum += __shfl_xor(sum, 32);
      const float inv = 1.0f / sum;

      // PV: O[q,d] = sum_k P[q,k] V[k,d]
      f32x4 o0 = {0.f, 0.f, 0.f, 0.f}, o1 = {0.f, 0.f, 0.f, 0.f};
      #pragma unroll
      for (int kk = 0; kk < 11; ++kk) {
        const short8 pf = ld8(&p_lds[wv][lr][kk * 32 + lg * 8]);
        const short8 v0 = ld8(vp + lr * VTP + kk * 32 + lg * 8);
        const short8 v1 = ld8(vp + (16 + lr) * VTP + kk * 32 + lg * 8);
        o0 = __builtin_amdgcn_mfma_f32_16x16x32_bf16(pf, v0, o0, 0, 0, 0);
        o1 = __builtin_amdgcn_mfma_f32_16x16x32_bf16(pf, v1, o1, 0, 0, 0);
      }

      // redistribute 1/sum to O's row mapping, store
      float invr[4];
      #pragma unroll
      for (int r = 0; r < 4; ++r)
        invr[r] = __shfl(inv, (lane & 48) | (lg * 4 + r));
      #pragma unroll
      for (int r = 0; r < 4; ++r) {
        const int n = row0 + lg * 4 + r;
        if (n < NTOK) {
          unsigned short* op = attn_out + (b * NTOK + n) * 192 + h * 32;
          op[lr]      = f2bf(o0[r] * invr[r]);
          op[16 + lr] = f2bf(o1[r] * invr[r]);
        }
      }
    }
  }
}

// ---------------- kernel D: output projection (bf16 GEMM, 128x192 tile/block) ----------------
__global__ __launch_bounds__(256) void proj_out(
    const unsigned short* __restrict__ a_in, const unsigned short* __restrict__ wp_bf,
    const float* __restrict__ pb, float* __restrict__ out)
{
  const int tid = threadIdx.x;
  const int wv = tid >> 6, lane = tid & 63, lg = lane >> 4, lr = lane & 15;
  const int row0 = blockIdx.x * 128 + wv * 32;

  f32x4 acc[2][12];
  #pragma unroll
  for (int i = 0; i < 2; ++i)
    #pragma unroll
    for (int j = 0; j < 12; ++j) acc[i][j] = (f32x4){0.f, 0.f, 0.f, 0.f};

  const unsigned short* xr0 = a_in + (row0 + lr) * 192;
  const unsigned short* xr1 = xr0 + 16 * 192;
  const unsigned short* wr  = wp_bf + lr * 192;

  #pragma unroll
  for (int kk = 0; kk < 6; ++kk) {
    const int k0 = kk * 32 + lg * 8;
    const short8 a0 = ld8(xr0 + k0);
    const short8 a1 = ld8(xr1 + k0);
    #pragma unroll
    for (int ct = 0; ct < 12; ++ct) {
      const short8 wf = ld8(wr + ct * 3072 + k0);
      acc[0][ct] = __builtin_amdgcn_mfma_f32_16x16x32_bf16(a0, wf, acc[0][ct], 0, 0, 0);
      acc[1][ct] = __builtin_amdgcn_mfma_f32_16x16x32_bf16(a1, wf, acc[1][ct], 0, 0, 0);
    }
  }

  float bs[12];
  #pragma unroll
  for (int ct = 0; ct < 12; ++ct) bs[ct] = pb[ct * 16 + lr];
  #pragma unroll
  for (int rs = 0; rs < 2; ++rs) {
    #pragma unroll
    for (int r = 0; r < 4; ++r) {
      const int t = row0 + rs * 16 + lg * 4 + r;
      float* op = out + t * 192 + lr;
      #pragma unroll
      for (int ct = 0; ct < 12; ++ct)
        op[ct * 16] = acc[rs][ct][r] + bs[ct];
    }
  }
}

extern "C" void kernel_launch(void* const* d_in, const int* in_sizes, int n_in,
                              void* d_out, int out_size, void* d_ws, size_t ws_size,
                              hipStream_t stream) {
  const float* x1    = (const float*)d_in[0];
  const float* x2    = (const float*)d_in[1];
  const float* mask  = (const float*)d_in[2];
  const float* table = (const float*)d_in[3];
  const float* qw    = (const float*)d_in[4];
  const float* qb    = (const float*)d_in[5];
  const float* kvw   = (const float*)d_in[6];
  const float* kvb   = (const float*)d_in[7];
  const float* pw    = (const float*)d_in[8];
  const float* pb    = (const float*)d_in[9];
  const int* rel_idx = (const int*)d_in[10];

  char* ws = (char*)d_ws;
  unsigned short* q_g     = (unsigned short*)(ws + OFF_QG);
  unsigned short* k_g     = (unsigned short*)(ws + OFF_KG);
  unsigned short* v_t     = (unsigned short*)(ws + OFF_VT);
  unsigned short* a_o     = (unsigned short*)(ws + OFF_AO);   // x1b then attn out
  unsigned short* bias_bf = (unsigned short*)(ws + OFF_BIAS);
  unsigned short* mask_bf = (unsigned short*)(ws + OFF_MASK);
  unsigned short* wq_bf   = (unsigned short*)(ws + OFF_WB);
  unsigned short* wkv_bf  = wq_bf + 36864;
  unsigned short* wp_bf   = wkv_bf + 73728;
  unsigned short* x1b     = a_o;                               // aliased (dead after proj)
  unsigned short* x2b     = (unsigned short*)d_out;            // aliased (d_out written last)

  hipLaunchKernelGGL(precompute, dim3(41099), dim3(256), 0, stream,
                     x1, x2, mask, table, rel_idx, qw, kvw, pw,
                     x1b, x2b, wq_bf, wkv_bf, wp_bf, bias_bf, mask_bf, v_t);
  hipLaunchKernelGGL(proj, dim3(686, 3), dim3(256), 0, stream,
                     x1b, x2b, wq_bf, wkv_bf, qb, kvb, q_g, k_g, v_t);
  hipLaunchKernelGGL(attn, dim3(768), dim3(256), 0, stream,
                     q_g, k_g, v_t, bias_bf, mask_bf, a_o);
  hipLaunchKernelGGL(proj_out, dim3(686), dim3(256), 0, stream,
                     a_o, wp_bf, pb, (float*)d_out);
}

// Round 3
// 373.071 us; speedup vs baseline: 1.2888x; 1.0257x over previous
//
#include <hip/hip_runtime.h>

typedef __attribute__((ext_vector_type(8))) short short8;
typedef __attribute__((ext_vector_type(4))) float f32x4;
typedef __attribute__((ext_vector_type(4))) unsigned short us4;
typedef __attribute__((ext_vector_type(2))) unsigned int u32x2;

#define NTOK 343
#define BMP 352      // bias/mask padded row pitch (elements)
#define VTP 352      // v_t padded row pitch (elements)
#define LOG2E 1.4426950408889634f

// ---- workspace layout (bytes) ----
#define OFF_QG   0u
#define OFF_KG   33718272u     // 256*6*343*32*2
#define OFF_VT   67436544u
#define OFF_AO   102039552u    // x1b during precompute/proj; a_o afterwards
#define OFF_WB   135757824u    // bf16 weights: wq(73728) | wkv(147456) | wp(73728)
// bias_bf/mask_bf live in spare d_out space (d_out is 67.4MB, x2b uses 33.7MB)

__device__ __forceinline__ unsigned short f2bf(float f) {
  union { float f; unsigned u; } v; v.f = f;
  unsigned r = v.u + 0x7FFFu + ((v.u >> 16) & 1u);
  return (unsigned short)(r >> 16);
}

__device__ __forceinline__ float bf2f(unsigned short b) {
  union { unsigned u; float f; } v; v.u = ((unsigned)b) << 16;
  return v.f;
}

__device__ __forceinline__ short8 ld8(const unsigned short* p) {
  return *reinterpret_cast<const short8*>(p);
}

__device__ __forceinline__ float fexp2(float x) {
  float r; asm("v_exp_f32 %0, %1" : "=v"(r) : "v"(x)); return r;
}

__device__ __forceinline__ unsigned cvtpk(float a, float b) {
  unsigned r; asm("v_cvt_pk_bf16_f32 %0, %1, %2" : "=v"(r) : "v"(a), "v"(b)); return r;
}

// ---------------- kernel B: precompute ----------------
// task ranges (1 task per thread):
//  [0, 4214784)           x1 -> x1b (vec4)
//  [4214784, 8429568)     x2 -> x2b (vec4)
//  [8429568, 8466432)     weights -> bf16 (vec4)
//  [8466432, 10398208)    mask -> mask_bf * LOG2E (21952 rows x 88 quads, pad-zeroed)
//  [10398208, 10515857)   bias gather * LOG2E (117649, x6 heads)
//  [10515857, 10517915)   bias pad zero (2058 rows x 9)
//  [10517915, 10567067)   v_t pad zero (49152 rows x 9)
__global__ __launch_bounds__(256) void precompute(
    const float* __restrict__ x1, const float* __restrict__ x2,
    const float* __restrict__ mask, const float* __restrict__ table,
    const int* __restrict__ rel_idx,
    const float* __restrict__ qw, const float* __restrict__ kvw, const float* __restrict__ pw,
    unsigned short* __restrict__ x1b, unsigned short* __restrict__ x2b,
    unsigned short* __restrict__ wq_bf, unsigned short* __restrict__ wkv_bf,
    unsigned short* __restrict__ wp_bf,
    unsigned short* __restrict__ bias_bf, unsigned short* __restrict__ mask_bf,
    unsigned short* __restrict__ v_t)
{
  const int idx = blockIdx.x * 256 + threadIdx.x;
  if (idx < 8429568) {
    const float* src; unsigned short* dst; int i;
    if (idx < 4214784) { src = x1; dst = x1b; i = idx; }
    else               { src = x2; dst = x2b; i = idx - 4214784; }
    f32x4 v = *reinterpret_cast<const f32x4*>(src + i * 4);
    us4 o; o[0] = f2bf(v[0]); o[1] = f2bf(v[1]); o[2] = f2bf(v[2]); o[3] = f2bf(v[3]);
    *reinterpret_cast<us4*>(dst + i * 4) = o;
  } else if (idx < 8466432) {
    const int wi = idx - 8429568;
    const float* src; unsigned short* dst; int i;
    if (wi < 9216)       { src = qw;  dst = wq_bf;  i = wi; }
    else if (wi < 27648) { src = kvw; dst = wkv_bf; i = wi - 9216; }
    else                 { src = pw;  dst = wp_bf;  i = wi - 27648; }
    f32x4 v = *reinterpret_cast<const f32x4*>(src + i * 4);
    us4 o; o[0] = f2bf(v[0]); o[1] = f2bf(v[1]); o[2] = f2bf(v[2]); o[3] = f2bf(v[3]);
    *reinterpret_cast<us4*>(dst + i * 4) = o;
  } else if (idx < 10398208) {
    const int mi = idx - 8466432;
    const int row = mi / 88, q = mi - row * 88;
    const int j0 = q * 4;
    unsigned short* dst = mask_bf + row * BMP + j0;
    if (q < 85) {
      const float* src = mask + row * NTOK + j0;
      us4 o; o[0] = f2bf(LOG2E * src[0]); o[1] = f2bf(LOG2E * src[1]);
      o[2] = f2bf(LOG2E * src[2]); o[3] = f2bf(LOG2E * src[3]);
      *reinterpret_cast<us4*>(dst) = o;
    } else {
      us4 o;
      #pragma unroll
      for (int i = 0; i < 4; ++i) {
        const int col = j0 + i;
        o[i] = (col < NTOK) ? f2bf(LOG2E * mask[row * NTOK + col]) : (unsigned short)0;
      }
      *reinterpret_cast<us4*>(dst) = o;
    }
  } else if (idx < 10515857) {
    const int i = idx - 10398208;
    const int ri = rel_idx[i] * 6;
    const int rrow = i / NTOK, j = i - rrow * NTOK;
    unsigned short* dst = bias_bf + rrow * BMP + j;
    #pragma unroll
    for (int h = 0; h < 6; ++h) dst[h * (NTOK * BMP)] = f2bf(LOG2E * table[ri + h]);
  } else if (idx < 10517915) {
    const int p = idx - 10515857;
    unsigned short* dst = bias_bf + p * BMP + NTOK;
    #pragma unroll
    for (int c = 0; c < 9; ++c) dst[c] = 0;
  } else if (idx < 10567067) {
    const int row = idx - 10517915;
    unsigned short* dst = v_t + row * VTP + NTOK;
    #pragma unroll
    for (int c = 0; c < 9; ++c) dst[c] = 0;
  }
}

// ---------------- kernel A: fused Q/K/V projection (bf16 GEMM, 128x192 tile/block) ----------------
__global__ __launch_bounds__(256) void proj(
    const unsigned short* __restrict__ x1b, const unsigned short* __restrict__ x2b,
    const unsigned short* __restrict__ wq_bf, const unsigned short* __restrict__ wkv_bf,
    const float* __restrict__ qb, const float* __restrict__ kvb,
    unsigned short* __restrict__ q_g, unsigned short* __restrict__ k_g,
    unsigned short* __restrict__ v_t)
{
  const int tid = threadIdx.x;
  const int wv = tid >> 6, lane = tid & 63, lg = lane >> 4, lr = lane & 15;
  const int path = blockIdx.y;
  const int row0 = blockIdx.x * 128 + wv * 32;

  const unsigned short* X = (path == 0) ? x1b : x2b;
  const unsigned short* W = (path == 0) ? wq_bf : (path == 1 ? wkv_bf : wkv_bf + 36864);
  const float* Bv = (path == 0) ? qb : (path == 1 ? kvb : kvb + 192);

  f32x4 acc[2][12];
  #pragma unroll
  for (int i = 0; i < 2; ++i)
    #pragma unroll
    for (int j = 0; j < 12; ++j) acc[i][j] = (f32x4){0.f, 0.f, 0.f, 0.f};

  const unsigned short* xr0 = X + (row0 + lr) * 192;
  const unsigned short* xr1 = xr0 + 16 * 192;
  const unsigned short* wr  = W + lr * 192;

  if (path < 2) {
    #pragma unroll
    for (int kk = 0; kk < 6; ++kk) {
      const int k0 = kk * 32 + lg * 8;
      const short8 a0 = ld8(xr0 + k0);
      const short8 a1 = ld8(xr1 + k0);
      #pragma unroll
      for (int ct = 0; ct < 12; ++ct) {
        const short8 wf = ld8(wr + ct * 3072 + k0);
        acc[0][ct] = __builtin_amdgcn_mfma_f32_16x16x32_bf16(a0, wf, acc[0][ct], 0, 0, 0);
        acc[1][ct] = __builtin_amdgcn_mfma_f32_16x16x32_bf16(a1, wf, acc[1][ct], 0, 0, 0);
      }
    }
    unsigned short* out = (path == 0) ? q_g : k_g;
    // Q gets scale * log2e folded in (softmax uses exp2)
    const float scale = (path == 0) ? (0.17677669529663687f * LOG2E) : 1.0f;
    float bs[12];
    #pragma unroll
    for (int ct = 0; ct < 12; ++ct) bs[ct] = Bv[ct * 16 + lr];
    #pragma unroll
    for (int rs = 0; rs < 2; ++rs) {
      const int t0 = row0 + rs * 16 + lg * 4;
      const int b0 = t0 / NTOK;
      const int n0 = t0 - b0 * NTOK;
      #pragma unroll
      for (int r = 0; r < 4; ++r) {
        int b = b0, n = n0 + r;
        if (n >= NTOK) { b++; n -= NTOK; }
        unsigned short* ob = out + (b * 6 * NTOK + n) * 32 + lr;
        #pragma unroll
        for (int ct = 0; ct < 12; ++ct) {
          const int h = ct >> 1, dhi = (ct & 1) * 16;
          ob[h * (NTOK * 32) + dhi] = f2bf((acc[rs][ct][r] + bs[ct]) * scale);
        }
      }
    }
  } else {
    #pragma unroll
    for (int kk = 0; kk < 6; ++kk) {
      const int k0 = kk * 32 + lg * 8;
      const short8 a0 = ld8(xr0 + k0);
      const short8 a1 = ld8(xr1 + k0);
      #pragma unroll
      for (int ct = 0; ct < 12; ++ct) {
        const short8 wf = ld8(wr + ct * 3072 + k0);
        acc[0][ct] = __builtin_amdgcn_mfma_f32_16x16x32_bf16(wf, a0, acc[0][ct], 0, 0, 0);
        acc[1][ct] = __builtin_amdgcn_mfma_f32_16x16x32_bf16(wf, a1, acc[1][ct], 0, 0, 0);
      }
    }
    f32x4 bv[12];
    #pragma unroll
    for (int ct = 0; ct < 12; ++ct)
      bv[ct] = *reinterpret_cast<const f32x4*>(Bv + ct * 16 + lg * 4);
    #pragma unroll
    for (int tt = 0; tt < 2; ++tt) {
      const int t = row0 + tt * 16 + lr;
      const int b = t / NTOK;
      const int n = t - b * NTOK;
      unsigned short* vb = v_t + b * (6 * 32 * VTP) + n;
      #pragma unroll
      for (int ct = 0; ct < 12; ++ct) {
        unsigned short* vc = vb + (ct * 16 + lg * 4) * VTP;
        #pragma unroll
        for (int r = 0; r < 4; ++r) {
          vc[r * VTP] = f2bf(acc[tt][ct][r] + bv[ct][r]);
        }
      }
    }
  }
}

// ---------------- kernel C: attention v3 ----------------
// one block per (b,h); K staged in LDS once; V from global (L2-resident);
// P chunked through per-wave LDS; 3 blocks/CU (LDS 53760B).
__global__ __launch_bounds__(256, 3) void attn(
    const unsigned short* __restrict__ q_g, const unsigned short* __restrict__ k_g,
    const unsigned short* __restrict__ v_t, const unsigned short* __restrict__ bias_bf,
    const unsigned short* __restrict__ mask_bf, unsigned short* __restrict__ attn_out)
{
  __shared__ __align__(16) unsigned short kLds[352][40];
  __shared__ __align__(16) unsigned short pLds[4][16][200];

  const int tid = threadIdx.x;
  const int wv = tid >> 6, lane = tid & 63, lg = lane >> 4, lr = lane & 15;
  const int bid = blockIdx.x;
  const int b = bid / 6, h = bid - b * 6;
  const int w = b & 63;

  const unsigned short* qp = q_g + bid * (NTOK * 32);
  const unsigned short* kp = k_g + bid * (NTOK * 32);
  const unsigned short* vp = v_t + bid * (32 * VTP);
  const unsigned short* bias_h = bias_bf + h * (NTOK * BMP);
  const unsigned short* mask_w = mask_bf + w * (NTOK * BMP);

  // stage K: 343 rows x 32 elems -> [352][40] padded (rows 343..351 uninit, masked later)
  for (int c = tid; c < 1372; c += 256)
    *reinterpret_cast<short8*>(&kLds[c >> 2][(c & 3) * 8]) = ld8(kp + c * 8);
  __syncthreads();

  for (int it = 0; it < 6; ++it) {
    const int t = it * 4 + wv;          // row-tile 0..21
    if (t >= 22) break;                 // wave-uniform
    const int q0 = t * 16;
    const int qrow = q0 + lr;
    const int qrc = qrow < NTOK ? qrow : NTOK - 1;
    const short8 qf = ld8(qp + qrc * 32 + lg * 8);
    const unsigned short* bmb = bias_h + qrc * BMP;
    const unsigned short* bmm = mask_w + qrc * BMP;

    // S^T = K @ Q^T : lane holds S[k = j*16+lg*4+r][q = q0+lr]
    f32x4 s[22];
    #pragma unroll
    for (int j = 0; j < 22; ++j) {
      const short8 kf = ld8(&kLds[j * 16 + lr][lg * 8]);
      const f32x4 z = {0.f, 0.f, 0.f, 0.f};
      s[j] = __builtin_amdgcn_mfma_f32_16x16x32_bf16(kf, qf, z, 0, 0, 0);
    }

    // bias+mask (pre-scaled by log2e) + max
    float mx = -1e30f;
    #pragma unroll
    for (int j = 0; j < 22; ++j) {
      const int kb = j * 16 + lg * 4;
      const us4 b4 = *reinterpret_cast<const us4*>(bmb + kb);
      const us4 m4 = *reinterpret_cast<const us4*>(bmm + kb);
      #pragma unroll
      for (int r = 0; r < 4; ++r) {
        float v = s[j][r] + (bf2f(b4[r]) + bf2f(m4[r]));
        if (j == 21) v = (kb + r < NTOK) ? v : -1e30f;
        s[j][r] = v;
        mx = fmaxf(mx, v);
      }
    }
    mx = fmaxf(mx, __shfl_xor(mx, 16));
    mx = fmaxf(mx, __shfl_xor(mx, 32));

    float sum = 0.f;
    f32x4 o0 = {0.f, 0.f, 0.f, 0.f}, o1 = {0.f, 0.f, 0.f, 0.f};

    // chunk A: k tiles 0..11 (k 0..191)
    #pragma unroll
    for (int j = 0; j < 12; ++j) {
      const float p0 = fexp2(s[j][0] - mx), p1 = fexp2(s[j][1] - mx);
      const float p2 = fexp2(s[j][2] - mx), p3 = fexp2(s[j][3] - mx);
      sum += (p0 + p1) + (p2 + p3);
      u32x2 pw; pw[0] = cvtpk(p0, p1); pw[1] = cvtpk(p2, p3);
      *reinterpret_cast<u32x2*>(&pLds[wv][lr][j * 16 + lg * 4]) = pw;
    }
    #pragma unroll
    for (int kk = 0; kk < 6; ++kk) {
      const short8 pf = ld8(&pLds[wv][lr][kk * 32 + lg * 8]);
      const short8 v0 = ld8(vp + lr * VTP + kk * 32 + lg * 8);
      const short8 v1 = ld8(vp + (16 + lr) * VTP + kk * 32 + lg * 8);
      o0 = __builtin_amdgcn_mfma_f32_16x16x32_bf16(pf, v0, o0, 0, 0, 0);
      o1 = __builtin_amdgcn_mfma_f32_16x16x32_bf16(pf, v1, o1, 0, 0, 0);
    }
    // chunk B: k tiles 12..21 (k 192..351)
    #pragma unroll
    for (int j = 12; j < 22; ++j) {
      const float p0 = fexp2(s[j][0] - mx), p1 = fexp2(s[j][1] - mx);
      const float p2 = fexp2(s[j][2] - mx), p3 = fexp2(s[j][3] - mx);
      sum += (p0 + p1) + (p2 + p3);
      u32x2 pw; pw[0] = cvtpk(p0, p1); pw[1] = cvtpk(p2, p3);
      *reinterpret_cast<u32x2*>(&pLds[wv][lr][(j - 12) * 16 + lg * 4]) = pw;
    }
    #pragma unroll
    for (int kk = 6; kk < 11; ++kk) {
      const short8 pf = ld8(&pLds[wv][lr][(kk - 6) * 32 + lg * 8]);
      const short8 v0 = ld8(vp + lr * VTP + kk * 32 + lg * 8);
      const short8 v1 = ld8(vp + (16 + lr) * VTP + kk * 32 + lg * 8);
      o0 = __builtin_amdgcn_mfma_f32_16x16x32_bf16(pf, v0, o0, 0, 0, 0);
      o1 = __builtin_amdgcn_mfma_f32_16x16x32_bf16(pf, v1, o1, 0, 0, 0);
    }

    sum += __shfl_xor(sum, 16);
    sum += __shfl_xor(sum, 32);
    const float inv = 1.0f / sum;
    float invr[4];
    #pragma unroll
    for (int r = 0; r < 4; ++r)
      invr[r] = __shfl(inv, (lane & 48) | (lg * 4 + r));
    #pragma unroll
    for (int r = 0; r < 4; ++r) {
      const int n = q0 + lg * 4 + r;
      if (n < NTOK) {
        unsigned short* op = attn_out + (b * NTOK + n) * 192 + h * 32;
        op[lr]      = f2bf(o0[r] * invr[r]);
        op[16 + lr] = f2bf(o1[r] * invr[r]);
      }
    }
  }
}

// ---------------- kernel D: output projection ----------------
__global__ __launch_bounds__(256) void proj_out(
    const unsigned short* __restrict__ a_in, const unsigned short* __restrict__ wp_bf,
    const float* __restrict__ pb, float* __restrict__ out)
{
  const int tid = threadIdx.x;
  const int wv = tid >> 6, lane = tid & 63, lg = lane >> 4, lr = lane & 15;
  const int row0 = blockIdx.x * 128 + wv * 32;

  f32x4 acc[2][12];
  #pragma unroll
  for (int i = 0; i < 2; ++i)
    #pragma unroll
    for (int j = 0; j < 12; ++j) acc[i][j] = (f32x4){0.f, 0.f, 0.f, 0.f};

  const unsigned short* xr0 = a_in + (row0 + lr) * 192;
  const unsigned short* xr1 = xr0 + 16 * 192;
  const unsigned short* wr  = wp_bf + lr * 192;

  #pragma unroll
  for (int kk = 0; kk < 6; ++kk) {
    const int k0 = kk * 32 + lg * 8;
    const short8 a0 = ld8(xr0 + k0);
    const short8 a1 = ld8(xr1 + k0);
    #pragma unroll
    for (int ct = 0; ct < 12; ++ct) {
      const short8 wf = ld8(wr + ct * 3072 + k0);
      acc[0][ct] = __builtin_amdgcn_mfma_f32_16x16x32_bf16(a0, wf, acc[0][ct], 0, 0, 0);
      acc[1][ct] = __builtin_amdgcn_mfma_f32_16x16x32_bf16(a1, wf, acc[1][ct], 0, 0, 0);
    }
  }

  float bs[12];
  #pragma unroll
  for (int ct = 0; ct < 12; ++ct) bs[ct] = pb[ct * 16 + lr];
  #pragma unroll
  for (int rs = 0; rs < 2; ++rs) {
    #pragma unroll
    for (int r = 0; r < 4; ++r) {
      const int t = row0 + rs * 16 + lg * 4 + r;
      float* op = out + t * 192 + lr;
      #pragma unroll
      for (int ct = 0; ct < 12; ++ct)
        op[ct * 16] = acc[rs][ct][r] + bs[ct];
    }
  }
}

extern "C" void kernel_launch(void* const* d_in, const int* in_sizes, int n_in,
                              void* d_out, int out_size, void* d_ws, size_t ws_size,
                              hipStream_t stream) {
  const float* x1    = (const float*)d_in[0];
  const float* x2    = (const float*)d_in[1];
  const float* mask  = (const float*)d_in[2];
  const float* table = (const float*)d_in[3];
  const float* qw    = (const float*)d_in[4];
  const float* qb    = (const float*)d_in[5];
  const float* kvw   = (const float*)d_in[6];
  const float* kvb   = (const float*)d_in[7];
  const float* pw    = (const float*)d_in[8];
  const float* pb    = (const float*)d_in[9];
  const int* rel_idx = (const int*)d_in[10];

  char* ws = (char*)d_ws;
  char* outc = (char*)d_out;
  unsigned short* q_g     = (unsigned short*)(ws + OFF_QG);
  unsigned short* k_g     = (unsigned short*)(ws + OFF_KG);
  unsigned short* v_t     = (unsigned short*)(ws + OFF_VT);
  unsigned short* a_o     = (unsigned short*)(ws + OFF_AO);   // x1b then attn out
  unsigned short* wq_bf   = (unsigned short*)(ws + OFF_WB);
  unsigned short* wkv_bf  = wq_bf + 36864;
  unsigned short* wp_bf   = wkv_bf + 73728;
  unsigned short* x1b     = a_o;                               // aliased (dead after proj)
  unsigned short* x2b     = (unsigned short*)outc;             // aliased (d_out written last)
  unsigned short* bias_bf = (unsigned short*)(outc + 33718272);// 6*343*352*2   = 1448832
  unsigned short* mask_bf = (unsigned short*)(outc + 35167104);// 64*343*352*2  = 15454208 (end 50.6MB < 67.4MB)

  hipLaunchKernelGGL(precompute, dim3(41278), dim3(256), 0, stream,
                     x1, x2, mask, table, rel_idx, qw, kvw, pw,
                     x1b, x2b, wq_bf, wkv_bf, wp_bf, bias_bf, mask_bf, v_t);
  hipLaunchKernelGGL(proj, dim3(686, 3), dim3(256), 0, stream,
                     x1b, x2b, wq_bf, wkv_bf, qb, kvb, q_g, k_g, v_t);
  hipLaunchKernelGGL(attn, dim3(1536), dim3(256), 0, stream,
                     q_g, k_g, v_t, bias_bf, mask_bf, a_o);
  hipLaunchKernelGGL(proj_out, dim3(686), dim3(256), 0, stream,
                     a_o, wp_bf, pb, (float*)d_out);
}